// Round 1
// baseline (94.846 us; speedup 1.0000x reference)
//
#include <hip/hip_runtime.h>

// Edge scorer: out[e] = (dot(h[src],h[dst]) + bias[nid[src]] + bias[nid[dst]])
//                       * (1/pop[src]) * (1/pop[dst])
// 32 lanes per edge; lane j loads float4 at column j*4 of the 128-float row.

__global__ __launch_bounds__(256) void edge_score_kernel(
    const float* __restrict__ h,
    const float* __restrict__ pop,
    const float* __restrict__ bias,
    const int*   __restrict__ src,
    const int*   __restrict__ dst,
    const int*   __restrict__ nid,
    float*       __restrict__ out,
    int n_edges)
{
    const int gtid    = blockIdx.x * blockDim.x + threadIdx.x;
    const int group   = gtid >> 5;                       // one edge per 32 lanes
    const int lane    = threadIdx.x & 31;
    const int ngroups = (gridDim.x * blockDim.x) >> 5;

    for (int e = group; e < n_edges; e += ngroups) {
        const int si = src[e];
        const int di = dst[e];

        const float4 a = *reinterpret_cast<const float4*>(h + (size_t)si * 128 + lane * 4);
        const float4 b = *reinterpret_cast<const float4*>(h + (size_t)di * 128 + lane * 4);

        float part = a.x * b.x + a.y * b.y + a.z * b.z + a.w * b.w;

        // reduce across the 32-lane group (xor masks <= 16 stay in-half)
        part += __shfl_xor(part, 1);
        part += __shfl_xor(part, 2);
        part += __shfl_xor(part, 4);
        part += __shfl_xor(part, 8);
        part += __shfl_xor(part, 16);

        if (lane == 0) {
            const float ipw = (1.0f / pop[si]) * (1.0f / pop[di]);
            const float bb  = bias[nid[si]] + bias[nid[di]];
            out[e] = (part + bb) * ipw;
        }
    }
}

extern "C" void kernel_launch(void* const* d_in, const int* in_sizes, int n_in,
                              void* d_out, int out_size, void* d_ws, size_t ws_size,
                              hipStream_t stream) {
    const float* h    = (const float*)d_in[0];
    const float* pop  = (const float*)d_in[1];
    const float* bias = (const float*)d_in[2];
    const int*   src  = (const int*)d_in[3];
    const int*   dst  = (const int*)d_in[4];
    const int*   nid  = (const int*)d_in[5];
    float*       out  = (float*)d_out;

    const int n_edges = in_sizes[3];

    const int block = 256;                       // 8 edges per block per iter
    const int edges_per_block = block / 32;
    int grid = (n_edges + edges_per_block - 1) / edges_per_block;
    if (grid > 2048) grid = 2048;                // grid-stride beyond this

    edge_score_kernel<<<grid, block, 0, stream>>>(h, pop, bias, src, dst, nid,
                                                  out, n_edges);
}

// Round 2
// 81.492 us; speedup vs baseline: 1.1639x; 1.1639x over previous
//
#include <hip/hip_runtime.h>

// out[e] = (dot(h[src],h[dst]) + bias[nid[src]] + bias[nid[dst]]) / (pop[src]*pop[dst])
//
// Two-phase:
//   1) node_prep: nodeinfo[i] = float2(1/pop[i], bias[nid[i]])   (800 KB, L2-resident)
//   2) edge_score: 16 lanes per edge, each lane loads 2 float4 per row (32 B),
//      4-step shfl_xor reduce, lane 0 reads 2 cached float2 + stores.

__global__ __launch_bounds__(256) void node_prep_kernel(
    const float* __restrict__ pop,
    const float* __restrict__ bias,
    const int*   __restrict__ nid,
    float2*      __restrict__ nodeinfo,
    int n_nodes)
{
    int i = blockIdx.x * blockDim.x + threadIdx.x;
    if (i < n_nodes) {
        nodeinfo[i] = make_float2(1.0f / pop[i], bias[nid[i]]);
    }
}

__global__ __launch_bounds__(256) void edge_score_kernel(
    const float*  __restrict__ h,
    const float2* __restrict__ nodeinfo,
    const int*    __restrict__ src,
    const int*    __restrict__ dst,
    float*        __restrict__ out,
    int n_edges)
{
    const int gtid  = blockIdx.x * blockDim.x + threadIdx.x;
    const int e     = gtid >> 4;            // one edge per 16 lanes
    const int lane  = threadIdx.x & 15;

    if (e >= n_edges) return;

    const int si = src[e];
    const int di = dst[e];

    const float* ra = h + (size_t)si * 128 + lane * 8;
    const float* rb = h + (size_t)di * 128 + lane * 8;

    // 4 independent 16B loads per lane -> good MLP
    const float4 a0 = *reinterpret_cast<const float4*>(ra);
    const float4 a1 = *reinterpret_cast<const float4*>(ra + 4);
    const float4 b0 = *reinterpret_cast<const float4*>(rb);
    const float4 b1 = *reinterpret_cast<const float4*>(rb + 4);

    float part = a0.x * b0.x + a0.y * b0.y + a0.z * b0.z + a0.w * b0.w
               + a1.x * b1.x + a1.y * b1.y + a1.z * b1.z + a1.w * b1.w;

    // reduce across the 16-lane group
    part += __shfl_xor(part, 1);
    part += __shfl_xor(part, 2);
    part += __shfl_xor(part, 4);
    part += __shfl_xor(part, 8);

    if (lane == 0) {
        const float2 ns = nodeinfo[si];
        const float2 nd = nodeinfo[di];
        out[e] = (part + ns.y + nd.y) * (ns.x * nd.x);
    }
}

// Fallback (ws too small): original scalar-gather path with 16-lane groups.
__global__ __launch_bounds__(256) void edge_score_fallback_kernel(
    const float* __restrict__ h,
    const float* __restrict__ pop,
    const float* __restrict__ bias,
    const int*   __restrict__ src,
    const int*   __restrict__ dst,
    const int*   __restrict__ nid,
    float*       __restrict__ out,
    int n_edges)
{
    const int gtid  = blockIdx.x * blockDim.x + threadIdx.x;
    const int e     = gtid >> 4;
    const int lane  = threadIdx.x & 15;
    if (e >= n_edges) return;

    const int si = src[e];
    const int di = dst[e];

    const float* ra = h + (size_t)si * 128 + lane * 8;
    const float* rb = h + (size_t)di * 128 + lane * 8;
    const float4 a0 = *reinterpret_cast<const float4*>(ra);
    const float4 a1 = *reinterpret_cast<const float4*>(ra + 4);
    const float4 b0 = *reinterpret_cast<const float4*>(rb);
    const float4 b1 = *reinterpret_cast<const float4*>(rb + 4);

    float part = a0.x * b0.x + a0.y * b0.y + a0.z * b0.z + a0.w * b0.w
               + a1.x * b1.x + a1.y * b1.y + a1.z * b1.z + a1.w * b1.w;

    part += __shfl_xor(part, 1);
    part += __shfl_xor(part, 2);
    part += __shfl_xor(part, 4);
    part += __shfl_xor(part, 8);

    if (lane == 0) {
        const float ipw = (1.0f / pop[si]) * (1.0f / pop[di]);
        const float bb  = bias[nid[si]] + bias[nid[di]];
        out[e] = (part + bb) * ipw;
    }
}

extern "C" void kernel_launch(void* const* d_in, const int* in_sizes, int n_in,
                              void* d_out, int out_size, void* d_ws, size_t ws_size,
                              hipStream_t stream) {
    const float* h    = (const float*)d_in[0];
    const float* pop  = (const float*)d_in[1];
    const float* bias = (const float*)d_in[2];
    const int*   src  = (const int*)d_in[3];
    const int*   dst  = (const int*)d_in[4];
    const int*   nid  = (const int*)d_in[5];
    float*       out  = (float*)d_out;

    const int n_edges = in_sizes[3];
    const int n_nodes = in_sizes[1];          // pop is [N_NODES, 1]

    const size_t ws_needed = (size_t)n_nodes * sizeof(float2);

    if (ws_size >= ws_needed) {
        float2* nodeinfo = (float2*)d_ws;

        int pgrid = (n_nodes + 255) / 256;
        node_prep_kernel<<<pgrid, 256, 0, stream>>>(pop, bias, nid, nodeinfo, n_nodes);

        // 16 edges per 256-thread block, one edge per group (no grid-stride)
        int grid = (n_edges + 15) / 16;
        edge_score_kernel<<<grid, 256, 0, stream>>>(h, nodeinfo, src, dst, out, n_edges);
    } else {
        int grid = (n_edges + 15) / 16;
        edge_score_fallback_kernel<<<grid, 256, 0, stream>>>(h, pop, bias, src, dst, nid,
                                                             out, n_edges);
    }
}

// Round 3
// 55.664 us; speedup vs baseline: 1.7039x; 1.4640x over previous
//
#include <hip/hip_runtime.h>
#include <hip/hip_fp16.h>

// out[e] = (dot(h[src],h[dst]) + bias[nid[src]] + bias[nid[dst]]) / (pop[src]*pop[dst])
//
// Three-phase:
//   1) convert_h: h (f32, 51.2 MB) -> h16 (fp16, 25.6 MB) in d_ws.
//      Halves the random-gather footprint; L2-miss floor drops ~2x.
//   2) node_prep: nodeinfo[i] = float2(1/pop[i], bias[nid[i]])  (800 KB)
//   3) edge_score_f16: 8 lanes/edge, each lane loads 2 float4 (=16 halves)
//      per row, fp32 accumulate, 3-step shfl_xor reduce.

union H8 {
    float4  f4;
    __half2 h2[4];
};

__device__ inline float dot8(const H8& a, const H8& b) {
    float s = 0.0f;
#pragma unroll
    for (int k = 0; k < 4; ++k) {
        float2 fa = __half22float2(a.h2[k]);
        float2 fb = __half22float2(b.h2[k]);
        s += fa.x * fb.x + fa.y * fb.y;
    }
    return s;
}

__global__ __launch_bounds__(256) void convert_h_kernel(
    const float* __restrict__ h,
    __half*      __restrict__ h16,
    int n_elems)                      // N_NODES*128, divisible by 8
{
    int i = blockIdx.x * blockDim.x + threadIdx.x;
    int base = i * 8;
    if (base < n_elems) {
        const float4 f0 = *reinterpret_cast<const float4*>(h + base);
        const float4 f1 = *reinterpret_cast<const float4*>(h + base + 4);
        H8 o;
        o.h2[0] = __floats2half2_rn(f0.x, f0.y);
        o.h2[1] = __floats2half2_rn(f0.z, f0.w);
        o.h2[2] = __floats2half2_rn(f1.x, f1.y);
        o.h2[3] = __floats2half2_rn(f1.z, f1.w);
        *reinterpret_cast<float4*>(h16 + base) = o.f4;
    }
}

__global__ __launch_bounds__(256) void node_prep_kernel(
    const float* __restrict__ pop,
    const float* __restrict__ bias,
    const int*   __restrict__ nid,
    float2*      __restrict__ nodeinfo,
    int n_nodes)
{
    int i = blockIdx.x * blockDim.x + threadIdx.x;
    if (i < n_nodes) {
        nodeinfo[i] = make_float2(1.0f / pop[i], bias[nid[i]]);
    }
}

__global__ __launch_bounds__(256) void edge_score_f16_kernel(
    const __half* __restrict__ h16,
    const float2* __restrict__ nodeinfo,
    const int*    __restrict__ src,
    const int*    __restrict__ dst,
    float*        __restrict__ out,
    int n_edges)
{
    const int gtid = blockIdx.x * blockDim.x + threadIdx.x;
    const int e    = gtid >> 3;           // one edge per 8 lanes
    const int lane = threadIdx.x & 7;
    if (e >= n_edges) return;

    const int si = src[e];
    const int di = dst[e];

    // row = 128 halves = 256 B; 8 lanes x 32 B (2 float4) each
    const __half* ra = h16 + (size_t)si * 128 + lane * 16;
    const __half* rb = h16 + (size_t)di * 128 + lane * 16;

    H8 a0, a1, b0, b1;
    a0.f4 = *reinterpret_cast<const float4*>(ra);
    a1.f4 = *reinterpret_cast<const float4*>(ra + 8);
    b0.f4 = *reinterpret_cast<const float4*>(rb);
    b1.f4 = *reinterpret_cast<const float4*>(rb + 8);

    float part = dot8(a0, b0) + dot8(a1, b1);

    part += __shfl_xor(part, 1);
    part += __shfl_xor(part, 2);
    part += __shfl_xor(part, 4);

    if (lane == 0) {
        const float2 ns = nodeinfo[si];
        const float2 nd = nodeinfo[di];
        out[e] = (part + ns.y + nd.y) * (ns.x * nd.x);
    }
}

// ---- fallback paths (ws too small) ----

__global__ __launch_bounds__(256) void edge_score_f32_kernel(
    const float*  __restrict__ h,
    const float2* __restrict__ nodeinfo,
    const int*    __restrict__ src,
    const int*    __restrict__ dst,
    float*        __restrict__ out,
    int n_edges)
{
    const int gtid = blockIdx.x * blockDim.x + threadIdx.x;
    const int e    = gtid >> 4;
    const int lane = threadIdx.x & 15;
    if (e >= n_edges) return;

    const int si = src[e];
    const int di = dst[e];
    const float* ra = h + (size_t)si * 128 + lane * 8;
    const float* rb = h + (size_t)di * 128 + lane * 8;
    const float4 a0 = *reinterpret_cast<const float4*>(ra);
    const float4 a1 = *reinterpret_cast<const float4*>(ra + 4);
    const float4 b0 = *reinterpret_cast<const float4*>(rb);
    const float4 b1 = *reinterpret_cast<const float4*>(rb + 4);

    float part = a0.x * b0.x + a0.y * b0.y + a0.z * b0.z + a0.w * b0.w
               + a1.x * b1.x + a1.y * b1.y + a1.z * b1.z + a1.w * b1.w;

    part += __shfl_xor(part, 1);
    part += __shfl_xor(part, 2);
    part += __shfl_xor(part, 4);
    part += __shfl_xor(part, 8);

    if (lane == 0) {
        const float2 ns = nodeinfo[si];
        const float2 nd = nodeinfo[di];
        out[e] = (part + ns.y + nd.y) * (ns.x * nd.x);
    }
}

__global__ __launch_bounds__(256) void edge_score_fallback_kernel(
    const float* __restrict__ h,
    const float* __restrict__ pop,
    const float* __restrict__ bias,
    const int*   __restrict__ src,
    const int*   __restrict__ dst,
    const int*   __restrict__ nid,
    float*       __restrict__ out,
    int n_edges)
{
    const int gtid = blockIdx.x * blockDim.x + threadIdx.x;
    const int e    = gtid >> 4;
    const int lane = threadIdx.x & 15;
    if (e >= n_edges) return;

    const int si = src[e];
    const int di = dst[e];
    const float* ra = h + (size_t)si * 128 + lane * 8;
    const float* rb = h + (size_t)di * 128 + lane * 8;
    const float4 a0 = *reinterpret_cast<const float4*>(ra);
    const float4 a1 = *reinterpret_cast<const float4*>(ra + 4);
    const float4 b0 = *reinterpret_cast<const float4*>(rb);
    const float4 b1 = *reinterpret_cast<const float4*>(rb + 4);

    float part = a0.x * b0.x + a0.y * b0.y + a0.z * b0.z + a0.w * b0.w
               + a1.x * b1.x + a1.y * b1.y + a1.z * b1.z + a1.w * b1.w;

    part += __shfl_xor(part, 1);
    part += __shfl_xor(part, 2);
    part += __shfl_xor(part, 4);
    part += __shfl_xor(part, 8);

    if (lane == 0) {
        const float ipw = (1.0f / pop[si]) * (1.0f / pop[di]);
        const float bb  = bias[nid[si]] + bias[nid[di]];
        out[e] = (part + bb) * ipw;
    }
}

extern "C" void kernel_launch(void* const* d_in, const int* in_sizes, int n_in,
                              void* d_out, int out_size, void* d_ws, size_t ws_size,
                              hipStream_t stream) {
    const float* h    = (const float*)d_in[0];
    const float* pop  = (const float*)d_in[1];
    const float* bias = (const float*)d_in[2];
    const int*   src  = (const int*)d_in[3];
    const int*   dst  = (const int*)d_in[4];
    const int*   nid  = (const int*)d_in[5];
    float*       out  = (float*)d_out;

    const int n_edges = in_sizes[3];
    const int n_nodes = in_sizes[1];          // pop is [N_NODES, 1]
    const int n_elems = in_sizes[0];          // n_nodes * 128

    const size_t h16_bytes  = (size_t)n_elems * sizeof(__half);
    const size_t info_bytes = (size_t)n_nodes * sizeof(float2);

    if (ws_size >= h16_bytes + info_bytes) {
        __half* h16      = (__half*)d_ws;
        float2* nodeinfo = (float2*)((char*)d_ws + h16_bytes);

        int cgrid = (n_elems / 8 + 255) / 256;
        convert_h_kernel<<<cgrid, 256, 0, stream>>>(h, h16, n_elems);

        int pgrid = (n_nodes + 255) / 256;
        node_prep_kernel<<<pgrid, 256, 0, stream>>>(pop, bias, nid, nodeinfo, n_nodes);

        int grid = ((n_edges * 8) + 255) / 256;   // 8 lanes per edge
        edge_score_f16_kernel<<<grid, 256, 0, stream>>>(h16, nodeinfo, src, dst,
                                                        out, n_edges);
    } else if (ws_size >= info_bytes) {
        float2* nodeinfo = (float2*)d_ws;

        int pgrid = (n_nodes + 255) / 256;
        node_prep_kernel<<<pgrid, 256, 0, stream>>>(pop, bias, nid, nodeinfo, n_nodes);

        int grid = ((n_edges * 16) + 255) / 256;
        edge_score_f32_kernel<<<grid, 256, 0, stream>>>(h, nodeinfo, src, dst,
                                                        out, n_edges);
    } else {
        int grid = ((n_edges * 16) + 255) / 256;
        edge_score_fallback_kernel<<<grid, 256, 0, stream>>>(h, pop, bias, src, dst, nid,
                                                             out, n_edges);
    }
}